// Round 11
// baseline (99.209 us; speedup 1.0000x reference)
//
#include <hip/hip_runtime.h>
#include <cstdint>

#define NW 10
#define NOPS 30

typedef float v2fp __attribute__((ext_vector_type(2)));

// ---------------------------------------------------------------------------
// Constexpr numpy RNG (SeedSequence + PCG64 XSL-RR), canary-certified (R5/R6).
// ---------------------------------------------------------------------------
namespace {

typedef unsigned __int128 u128;

struct CRng { u128 state; u128 inc; bool has32; uint32_t cached; };

constexpr u128 PCG_MUL = (((u128)0x2360ED051FC65DA4ULL) << 64) | (u128)0x4385DF649FCCF645ULL;

constexpr void cr_step(CRng &r) { r.state = r.state * PCG_MUL + r.inc; }

constexpr uint64_t cr_out(u128 st) {
  uint64_t hi = (uint64_t)(st >> 64);
  uint64_t lo = (uint64_t)st;
  unsigned rot = (unsigned)(st >> 122) & 63u;
  uint64_t v = hi ^ lo;
  return (v >> rot) | (v << ((64u - rot) & 63u));
}

constexpr uint64_t cr_next64(CRng &r) { cr_step(r); return cr_out(r.state); }

constexpr uint32_t cr_next32(CRng &r) {
  if (r.has32) { r.has32 = false; return r.cached; }
  uint64_t v = cr_next64(r);
  r.has32 = true; r.cached = (uint32_t)(v >> 32);
  return (uint32_t)v;
}

constexpr CRng cr_seed(uint32_t ent) {
  uint32_t pool[4] = {0u, 0u, 0u, 0u};
  uint32_t hc = 0x43b0d7e5u;              // INIT_A
  for (int i = 0; i < 4; i++) {
    uint32_t v = (i == 0) ? ent : 0u;
    v ^= hc; hc *= 0x931e8875u; v *= hc; v ^= v >> 16;
    pool[i] = v;
  }
  for (int s = 0; s < 4; s++)
    for (int d = 0; d < 4; d++)
      if (s != d) {
        uint32_t v = pool[s];
        v ^= hc; hc *= 0x931e8875u; v *= hc; v ^= v >> 16;        // hashmix
        uint32_t res = 0xca01f9ddu * pool[d] - 0x4973f715u * v;   // mix (SUB)
        res ^= res >> 16;
        pool[d] = res;
      }
  uint32_t hb = 0x8b51f9ddu;              // INIT_B
  uint64_t s64[4] = {0ull, 0ull, 0ull, 0ull};
  for (int i = 0; i < 8; i++) {
    uint32_t d = pool[i & 3];
    d ^= hb; hb *= 0x58f38dedu; d *= hb; d ^= d >> 16;
    if (i & 1) s64[i >> 1] |= ((uint64_t)d << 32); else s64[i >> 1] = (uint64_t)d;
  }
  CRng r{};
  u128 initstate = (((u128)s64[0]) << 64) | (u128)s64[1];
  u128 initseq   = (((u128)s64[2]) << 64) | (u128)s64[3];
  r.state = 0; r.inc = (initseq << 1) | (u128)1;
  cr_step(r);
  r.state += initstate;
  cr_step(r);
  r.has32 = false; r.cached = 0u;
  return r;
}

constexpr uint32_t cr_lemire32(CRng &r, uint32_t rng) {
  uint32_t rng_excl = rng + 1u;
  uint64_t m = (uint64_t)cr_next32(r) * (uint64_t)rng_excl;
  uint32_t leftover = (uint32_t)m;
  if (leftover < rng_excl) {
    uint32_t threshold = (uint32_t)(0xFFFFFFFFu - rng) % rng_excl;
    while (leftover < threshold) {
      m = (uint64_t)cr_next32(r) * (uint64_t)rng_excl;
      leftover = (uint32_t)m;
    }
  }
  return (uint32_t)(m >> 32);
}

constexpr bool canary_pcg42() {
  CRng r = cr_seed(42u);
  double a = (double)(cr_next64(r) >> 11) * (1.0 / 9007199254740992.0);
  double b = (double)(cr_next64(r) >> 11) * (1.0 / 9007199254740992.0);
  double c = (double)(cr_next64(r) >> 11) * (1.0 / 9007199254740992.0);
  bool ok = (a > 0.77395603) && (a < 0.77395607);
  ok = ok && (b > 0.43887842) && (b < 0.43887846);
  ok = ok && (c > 0.85859790) && (c < 0.85859794);
  return ok;
}
static_assert(canary_pcg42(), "CANARY_PCG_SEED42_RANDOM_MISMATCH");

// ---- compile-time circuit (WIRE indices; kind 0 RX,1 RY,2 RZ,3 CNOT) ------
struct COp { int kind; int a; int b; int slot; };
struct Circ { COp op[NOPS]; };

constexpr Circ build_circuit() {
  Circ c{};
  CRng r = cr_seed(42u);
  for (int i = 0; i < NOPS; i++) {
    int k = (int)cr_lemire32(r, 3u);            // integers(0,4)
    if (k == 3) {
      uint32_t v8 = cr_lemire32(r, 8u);         // Floyd j=8
      uint32_t v9 = cr_lemire32(r, 9u);         // Floyd j=9
      uint32_t i0 = v8;
      uint32_t i1 = (v9 == v8) ? 9u : v9;
      uint32_t j = cr_lemire32(r, 1u);          // shuffle swap bit
      if (j == 0u) { uint32_t t = i0; i0 = i1; i1 = t; }
      c.op[i] = COp{3, (int)i0, (int)i1, i};    // a=control, b=target
    } else {
      int w = (int)cr_lemire32(r, 9u);          // integers(0,10)
      c.op[i] = COp{k, w, 0, i};
    }
  }
  return c;
}
constexpr Circ CC = build_circuit();

// ---------------------------------------------------------------------------
// Compile-time Heisenberg propagation (verified R10): H = sum_w hw_w
// (cZ Z + cX X + cY Y) back through the 30 ops; Y-strings dropped; unique
// strings grouped. upack = ternary half-indices (lo wires 0-4, hi 5-9):
// digit 0:none 1:sin 2:cos -> tlo | (thi << 8).
// meta: xm[0:10) | zm[10:20) | sign[20] | w[21:25) | src[25:27)
// ---------------------------------------------------------------------------
constexpr int MAXP = 16384;
constexpr int MAXU = 4096;

struct Tables {
  int np, nu, overflow;
  uint32_t pmeta[MAXP]; uint32_t pcm[MAXP]; uint32_t psm[MAXP];
  uint32_t upack[MAXU]; int ustart[MAXU + 1];
};

constexpr Tables build_tables() {
  Tables T{};
  uint32_t meta[MAXP] = {}; uint32_t cm[MAXP] = {}; uint32_t sm[MAXP] = {};
  int np = 0; int ovf = 0;
  for (int w = 0; w < NW; w++)
    for (int src = 0; src < 3; src++) {         // 0:cZ->Z, 1:cX->X, 2:cY->Y
      uint32_t xm = (src != 0) ? (1u << w) : 0u;
      uint32_t zm = (src != 1) ? (1u << w) : 0u;
      meta[np] = xm | (zm << 10) | ((uint32_t)w << 21) | ((uint32_t)src << 25);
      cm[np] = 0u; sm[np] = 0u; np++;
    }
  for (int k = NOPS - 1; k >= 0 && !ovf; k--) {
    const COp op = CC.op[k];
    if (op.kind == 3) {
      const int c = op.a, t = op.b;
      for (int p = 0; p < np; p++) {
        uint32_t m = meta[p];
        uint32_t xm = m & 1023u, zm = (m >> 10) & 1023u;
        uint32_t xc = (xm >> c) & 1u, zc = (zm >> c) & 1u;
        uint32_t xt = (xm >> t) & 1u, zt = (zm >> t) & 1u;
        uint32_t fl = xc & zt & (1u ^ (xt ^ zc));
        xm ^= xc << t;
        zm ^= zt << c;
        m = (m & ~(1023u | (1023u << 10))) | xm | (zm << 10);
        m ^= fl << 20;
        meta[p] = m;
      }
    } else {
      const int q = op.a, ax = op.kind, bit = op.slot;
      const int n0 = np;
      for (int p = 0; p < n0; p++) {
        uint32_t m = meta[p];
        uint32_t x = (m >> q) & 1u;
        uint32_t z = (m >> (10 + q)) & 1u;
        uint32_t viol = (ax == 0) ? z : (ax == 1) ? (x ^ z) : x;
        if (viol) {
          uint32_t nx = 0, nz = 0, fl = 0;
          if (ax == 0)      { if (x) { nx = 0; nz = 1; fl = 1; } else { nx = 1; nz = 1; fl = 0; } }
          else if (ax == 1) { if (x) { nx = 0; nz = 1; fl = 0; } else { nx = 1; nz = 0; fl = 1; } }
          else              { if (z) { nx = 1; nz = 0; fl = 0; } else { nx = 1; nz = 1; fl = 1; } }
          if (np >= MAXP) { ovf = 1; break; }
          uint32_t m2 = m;
          m2 &= ~((1u << q) | (1u << (10 + q)));
          m2 |= (nx << q) | (nz << (10 + q));
          m2 ^= fl << 20;
          meta[np] = m2; cm[np] = cm[p]; sm[np] = sm[p] | (1u << bit);
          np++;
          cm[p] |= 1u << bit;
        }
      }
    }
  }
  if (ovf) { T.overflow = 1; return T; }
  // Y-kill compact
  int n2 = 0;
  for (int p = 0; p < np; p++) {
    uint32_t m = meta[p];
    if ((m & 1023u) & ((m >> 10) & 1023u)) continue;
    meta[n2] = m; cm[n2] = cm[p]; sm[n2] = sm[p]; n2++;
  }
  np = n2;
  // stable 2-pass radix sort of indices by 20-bit key
  int idx[MAXP] = {}; int tmp[MAXP] = {};
  for (int i = 0; i < np; i++) idx[i] = i;
  int hist[1025] = {};
  for (int i = 0; i < 1025; i++) hist[i] = 0;
  for (int i = 0; i < np; i++) hist[1 + (meta[idx[i]] & 1023u)]++;
  for (int i = 0; i < 1024; i++) hist[i + 1] += hist[i];
  for (int i = 0; i < np; i++) tmp[hist[meta[idx[i]] & 1023u]++] = idx[i];
  for (int i = 0; i < 1025; i++) hist[i] = 0;
  for (int i = 0; i < np; i++) hist[1 + ((meta[tmp[i]] >> 10) & 1023u)]++;
  for (int i = 0; i < 1024; i++) hist[i + 1] += hist[i];
  for (int i = 0; i < np; i++) idx[hist[(meta[tmp[i]] >> 10) & 1023u]++] = tmp[i];
  // group + emit (upack = ternary half-indices of the key)
  constexpr int P3[5] = {1, 3, 9, 27, 81};
  int nu = 0; uint32_t prev = 0xFFFFFFFFu;
  for (int i = 0; i < np; i++) {
    int p = idx[i];
    uint32_t key = meta[p] & 0xFFFFFu;
    if (key != prev) {
      if (nu >= MAXU) { T.overflow = 2; return T; }
      uint32_t tlo = 0, thi = 0;
      for (int w = 0; w < 5; w++) {
        uint32_t d = ((key >> w) & 1u) ? 1u : (((key >> (10 + w)) & 1u) ? 2u : 0u);
        tlo += d * (uint32_t)P3[w];
      }
      for (int w = 5; w < 10; w++) {
        uint32_t d = ((key >> w) & 1u) ? 1u : (((key >> (10 + w)) & 1u) ? 2u : 0u);
        thi += d * (uint32_t)P3[w - 5];
      }
      T.upack[nu] = tlo | (thi << 8);
      T.ustart[nu] = i; prev = key; nu++;
    }
    T.pmeta[i] = meta[p]; T.pcm[i] = cm[p]; T.psm[i] = sm[p];
  }
  T.ustart[nu] = np;
  T.np = np; T.nu = nu; T.overflow = 0;
  return T;
}

constexpr Tables TT = build_tables();
static_assert(TT.overflow == 0, "PAULI_PATH_OVERFLOW");
static_assert(TT.nu >= 1 && TT.nu <= MAXU, "PAULI_UNIQUE_COUNT_OUT_OF_RANGE");
constexpr int NU = TT.nu;

// ws layout (floats): [0] count (int alias); pairs (C, upack) float2 at 16;
// W_eff at WOFF; const at WOFF+10.
constexpr int PAIRS_OFF = 16;
constexpr int WOFF = PAIRS_OFF + 2 * NU;

} // namespace

__device__ const Tables dTT = TT;

// ---------------------------------------------------------------------------
// Prep kernel (1 block x 256): trig + tail-fold Pauli coeffs -> per-unique
// C_u; prune |C| <= 1e-6 and compact (order-free) into (C, upack) pairs +
// count; MLP collapse.
// ---------------------------------------------------------------------------
__global__ __launch_bounds__(256) void prep_kernel(
    const float* __restrict__ rand_params,
    const float* __restrict__ rx_theta, const float* __restrict__ ry_theta,
    const float* __restrict__ head_w, const float* __restrict__ head_b,
    const float* __restrict__ w0, const float* __restrict__ b0,
    const float* __restrict__ w1, const float* __restrict__ b1,
    const float* __restrict__ w2, const float* __restrict__ b2,
    const float* __restrict__ w3, const float* __restrict__ b3,
    float* __restrict__ ws)
{
  const int tid = threadIdx.x;
  __shared__ float ct[32], st[32], abr[3], hwsh[10];
  __shared__ float r2[32], r1[64];
  __shared__ int lcnt;

  if (tid == 0) lcnt = 0;
  if (tid < NOPS) {
    float t = rand_params[tid];       // FULL angle for Heisenberg conjugation
    ct[tid] = cosf(t);
    st[tid] = sinf(t);
  }
  if (tid == 30) {
    // O = M^dag Z M, Pauli coeffs (verified R10):
    float tx = rx_theta[0], ty = ry_theta[0];
    abr[0] = cosf(tx) * cosf(ty);     // cZ
    abr[1] = -sinf(ty);               // cX
    abr[2] = sinf(tx) * cosf(ty);     // cY
  }
  if (tid < NW) hwsh[tid] = head_w[tid];
  __syncthreads();

  v2fp* pairs = (v2fp*)(ws + PAIRS_OFF);
  for (int u = tid; u < NU; u += 256) {
    float acc = 0.f;
    const int i0 = dTT.ustart[u], i1 = dTT.ustart[u + 1];
    for (int i = i0; i < i1; i++) {
      uint32_t m = dTT.pmeta[i];
      float v = hwsh[(m >> 21) & 15u] * abr[(m >> 25) & 3u];
      if (m & (1u << 20)) v = -v;
      uint32_t c = dTT.pcm[i];
      while (c) { int b = __builtin_ctz(c); v *= ct[b]; c &= c - 1u; }
      uint32_t s = dTT.psm[i];
      while (s) { int b = __builtin_ctz(s); v *= st[b]; s &= s - 1u; }
      acc += v;
    }
    if (fabsf(acc) > 1e-6f) {
      int id = atomicAdd(&lcnt, 1);
      v2fp p;
      p.x = acc;
      p.y = __uint_as_float(dTT.upack[u]);
      pairs[id] = p;
    }
  }
  __syncthreads();
  if (tid == 0) ((int*)ws)[0] = lcnt;

  // ---- MLP collapse (fully linear) ----
  if (tid < 32) {
    float acc = 0.f;
    for (int k = 0; k < 16; k++) acc += w3[k] * w2[k*32 + tid];
    r2[tid] = acc;
  }
  __syncthreads();
  if (tid < 64) {
    float acc = 0.f;
    for (int k = 0; k < 32; k++) acc += r2[k] * w1[k*64 + tid];
    r1[tid] = acc;
  }
  __syncthreads();
  if (tid < NW) {
    float acc = 0.f;
    for (int k = 0; k < 64; k++) acc += r1[k] * w0[k*NW + tid];
    ws[WOFF + tid] = acc;
  }
  if (tid == NW) {
    float acc = b3[0] + head_b[0];
    for (int k = 0; k < 16; k++) acc += w3[k] * b2[k];
    for (int k = 0; k < 32; k++) acc += r2[k] * b1[k];
    for (int k = 0; k < 64; k++) acc += r1[k] * b0[k];
    ws[WOFF + NW] = acc;
  }
}

// ---------------------------------------------------------------------------
// Eval kernel: one 64-lane wave per element. Per-wave private 2x243 LDS
// half-product tables (ternary: 0->1, 1->sin x, 2->cos x), built wave-
// synchronously (no barrier). Each string = C * Tlo[tlo] * Thi[thi].
// ---------------------------------------------------------------------------
__global__ __launch_bounds__(256) void qsim_kernel(
    const float* __restrict__ x,
    const float* __restrict__ ws,
    float* __restrict__ out,
    int bsz)
{
  __shared__ v2fp  Psh[NU];
  __shared__ float Tlo[4][256];
  __shared__ float Thi[4][256];

  const int tid = threadIdx.x;
  const int nu_eff = ((const int*)ws)[0];

  const v2fp* pairs = (const v2fp*)(ws + PAIRS_OFF);
  for (int i = tid; i < nu_eff; i += 256) Psh[i] = pairs[i];
  __syncthreads();

  const int wv = (int)((blockIdx.x * blockDim.x + tid) >> 6);
  const int lane = tid & 63;
  const int e = tid >> 6;
  if (wv >= bsz) return;
  const float* xe = x + wv * NW;

  float cz[NW], sx[NW];
#pragma unroll
  for (int w = 0; w < NW; w++) {
    float xv = xe[w];
    cz[w] = __cosf(xv);
    sx[w] = __sinf(xv);
  }

  // Build the two 243-entry half-product tables (wave-private region).
  for (int t = lane; t < 243; t += 64) {
    float vlo = 1.f, vhi = 1.f;
    int q = t;
#pragma unroll
    for (int w = 0; w < 5; w++) {
      int d = q % 3; q /= 3;
      vlo *= (d == 1) ? sx[w]     : ((d == 2) ? cz[w]     : 1.0f);
      vhi *= (d == 1) ? sx[w + 5] : ((d == 2) ? cz[w + 5] : 1.0f);
    }
    Tlo[e][t] = vlo;
    Thi[e][t] = vhi;
  }
  // wave-synchronous LDS: same wave writes then reads (lgkmcnt handles RAW)

  float acc = 0.f;
  for (int i = lane; i < nu_eff; i += 64) {
    v2fp pr = Psh[i];
    uint32_t pk = __float_as_uint(pr.y);
    acc += pr.x * Tlo[e][pk & 255u] * Thi[e][pk >> 8];
  }

#pragma unroll
  for (int m = 1; m < 64; m <<= 1) acc += __shfl_xor(acc, m);

  if (lane == 0) {
    float cc = ws[WOFF + NW];
#pragma unroll
    for (int w = 0; w < NW; w++) cc += xe[w] * ws[WOFF + w];
    out[wv] = acc + cc;
  }
}

extern "C" void kernel_launch(void* const* d_in, const int* in_sizes, int n_in,
                              void* d_out, int out_size, void* d_ws, size_t ws_size,
                              hipStream_t stream) {
  const float* x   = (const float*)d_in[0];
  const float* rp  = (const float*)d_in[1];
  const float* rxT = (const float*)d_in[2];
  const float* ryT = (const float*)d_in[3];
  const float* hw  = (const float*)d_in[4];
  const float* hb  = (const float*)d_in[5];
  const float* w0  = (const float*)d_in[6];
  const float* b0  = (const float*)d_in[7];
  const float* w1  = (const float*)d_in[8];
  const float* b1  = (const float*)d_in[9];
  const float* w2  = (const float*)d_in[10];
  const float* b2  = (const float*)d_in[11];
  const float* w3  = (const float*)d_in[12];
  const float* b3  = (const float*)d_in[13];
  const int bsz = in_sizes[0] / NW;

  float* ws = (float*)d_ws;

  hipLaunchKernelGGL(prep_kernel, dim3(1), dim3(256), 0, stream,
                     rp, rxT, ryT, hw, hb, w0, b0, w1, b1, w2, b2, w3, b3, ws);

  const int blocks = (bsz + 3) / 4; // 4 elements (waves) per 256-thread block
  hipLaunchKernelGGL(qsim_kernel, dim3(blocks), dim3(256), 0, stream,
                     x, ws, (float*)d_out, bsz);
}

// Round 12
// 94.656 us; speedup vs baseline: 1.0481x; 1.0481x over previous
//
#include <hip/hip_runtime.h>
#include <cstdint>

#define NW 10
#define NOPS 30

typedef float v2fp __attribute__((ext_vector_type(2)));

// ---------------------------------------------------------------------------
// Constexpr numpy RNG (SeedSequence + PCG64 XSL-RR), canary-certified (R5/R6).
// ---------------------------------------------------------------------------
namespace {

typedef unsigned __int128 u128;

struct CRng { u128 state; u128 inc; bool has32; uint32_t cached; };

constexpr u128 PCG_MUL = (((u128)0x2360ED051FC65DA4ULL) << 64) | (u128)0x4385DF649FCCF645ULL;

constexpr void cr_step(CRng &r) { r.state = r.state * PCG_MUL + r.inc; }

constexpr uint64_t cr_out(u128 st) {
  uint64_t hi = (uint64_t)(st >> 64);
  uint64_t lo = (uint64_t)st;
  unsigned rot = (unsigned)(st >> 122) & 63u;
  uint64_t v = hi ^ lo;
  return (v >> rot) | (v << ((64u - rot) & 63u));
}

constexpr uint64_t cr_next64(CRng &r) { cr_step(r); return cr_out(r.state); }

constexpr uint32_t cr_next32(CRng &r) {
  if (r.has32) { r.has32 = false; return r.cached; }
  uint64_t v = cr_next64(r);
  r.has32 = true; r.cached = (uint32_t)(v >> 32);
  return (uint32_t)v;
}

constexpr CRng cr_seed(uint32_t ent) {
  uint32_t pool[4] = {0u, 0u, 0u, 0u};
  uint32_t hc = 0x43b0d7e5u;              // INIT_A
  for (int i = 0; i < 4; i++) {
    uint32_t v = (i == 0) ? ent : 0u;
    v ^= hc; hc *= 0x931e8875u; v *= hc; v ^= v >> 16;
    pool[i] = v;
  }
  for (int s = 0; s < 4; s++)
    for (int d = 0; d < 4; d++)
      if (s != d) {
        uint32_t v = pool[s];
        v ^= hc; hc *= 0x931e8875u; v *= hc; v ^= v >> 16;        // hashmix
        uint32_t res = 0xca01f9ddu * pool[d] - 0x4973f715u * v;   // mix (SUB)
        res ^= res >> 16;
        pool[d] = res;
      }
  uint32_t hb = 0x8b51f9ddu;              // INIT_B
  uint64_t s64[4] = {0ull, 0ull, 0ull, 0ull};
  for (int i = 0; i < 8; i++) {
    uint32_t d = pool[i & 3];
    d ^= hb; hb *= 0x58f38dedu; d *= hb; d ^= d >> 16;
    if (i & 1) s64[i >> 1] |= ((uint64_t)d << 32); else s64[i >> 1] = (uint64_t)d;
  }
  CRng r{};
  u128 initstate = (((u128)s64[0]) << 64) | (u128)s64[1];
  u128 initseq   = (((u128)s64[2]) << 64) | (u128)s64[3];
  r.state = 0; r.inc = (initseq << 1) | (u128)1;
  cr_step(r);
  r.state += initstate;
  cr_step(r);
  r.has32 = false; r.cached = 0u;
  return r;
}

constexpr uint32_t cr_lemire32(CRng &r, uint32_t rng) {
  uint32_t rng_excl = rng + 1u;
  uint64_t m = (uint64_t)cr_next32(r) * (uint64_t)rng_excl;
  uint32_t leftover = (uint32_t)m;
  if (leftover < rng_excl) {
    uint32_t threshold = (uint32_t)(0xFFFFFFFFu - rng) % rng_excl;
    while (leftover < threshold) {
      m = (uint64_t)cr_next32(r) * (uint64_t)rng_excl;
      leftover = (uint32_t)m;
    }
  }
  return (uint32_t)(m >> 32);
}

constexpr bool canary_pcg42() {
  CRng r = cr_seed(42u);
  double a = (double)(cr_next64(r) >> 11) * (1.0 / 9007199254740992.0);
  double b = (double)(cr_next64(r) >> 11) * (1.0 / 9007199254740992.0);
  double c = (double)(cr_next64(r) >> 11) * (1.0 / 9007199254740992.0);
  bool ok = (a > 0.77395603) && (a < 0.77395607);
  ok = ok && (b > 0.43887842) && (b < 0.43887846);
  ok = ok && (c > 0.85859790) && (c < 0.85859794);
  return ok;
}
static_assert(canary_pcg42(), "CANARY_PCG_SEED42_RANDOM_MISMATCH");

// ---- compile-time circuit (WIRE indices; kind 0 RX,1 RY,2 RZ,3 CNOT) ------
struct COp { int kind; int a; int b; int slot; };
struct Circ { COp op[NOPS]; };

constexpr Circ build_circuit() {
  Circ c{};
  CRng r = cr_seed(42u);
  for (int i = 0; i < NOPS; i++) {
    int k = (int)cr_lemire32(r, 3u);            // integers(0,4)
    if (k == 3) {
      uint32_t v8 = cr_lemire32(r, 8u);         // Floyd j=8
      uint32_t v9 = cr_lemire32(r, 9u);         // Floyd j=9
      uint32_t i0 = v8;
      uint32_t i1 = (v9 == v8) ? 9u : v9;
      uint32_t j = cr_lemire32(r, 1u);          // shuffle swap bit
      if (j == 0u) { uint32_t t = i0; i0 = i1; i1 = t; }
      c.op[i] = COp{3, (int)i0, (int)i1, i};    // a=control, b=target
    } else {
      int w = (int)cr_lemire32(r, 9u);          // integers(0,10)
      c.op[i] = COp{k, w, 0, i};
    }
  }
  return c;
}
constexpr Circ CC = build_circuit();

// ---------------------------------------------------------------------------
// Compile-time Heisenberg propagation (verified R10): H = sum_w hw_w
// (cZ Z + cX X + cY Y) back through the 30 ops; Y-strings dropped; unique
// strings grouped. upack = ternary half-indices (lo wires 0-4, hi 5-9):
// digit 0:none 1:sin 2:cos -> tlo | (thi << 8).
// meta: xm[0:10) | zm[10:20) | sign[20] | w[21:25) | src[25:27)
// ---------------------------------------------------------------------------
constexpr int MAXP = 16384;
constexpr int MAXU = 4096;

struct Tables {
  int np, nu, overflow;
  uint32_t pmeta[MAXP]; uint32_t pcm[MAXP]; uint32_t psm[MAXP];
  uint32_t upack[MAXU]; int ustart[MAXU + 1];
};

constexpr Tables build_tables() {
  Tables T{};
  uint32_t meta[MAXP] = {}; uint32_t cm[MAXP] = {}; uint32_t sm[MAXP] = {};
  int np = 0; int ovf = 0;
  for (int w = 0; w < NW; w++)
    for (int src = 0; src < 3; src++) {         // 0:cZ->Z, 1:cX->X, 2:cY->Y
      uint32_t xm = (src != 0) ? (1u << w) : 0u;
      uint32_t zm = (src != 1) ? (1u << w) : 0u;
      meta[np] = xm | (zm << 10) | ((uint32_t)w << 21) | ((uint32_t)src << 25);
      cm[np] = 0u; sm[np] = 0u; np++;
    }
  for (int k = NOPS - 1; k >= 0 && !ovf; k--) {
    const COp op = CC.op[k];
    if (op.kind == 3) {
      const int c = op.a, t = op.b;
      for (int p = 0; p < np; p++) {
        uint32_t m = meta[p];
        uint32_t xm = m & 1023u, zm = (m >> 10) & 1023u;
        uint32_t xc = (xm >> c) & 1u, zc = (zm >> c) & 1u;
        uint32_t xt = (xm >> t) & 1u, zt = (zm >> t) & 1u;
        uint32_t fl = xc & zt & (1u ^ (xt ^ zc));
        xm ^= xc << t;
        zm ^= zt << c;
        m = (m & ~(1023u | (1023u << 10))) | xm | (zm << 10);
        m ^= fl << 20;
        meta[p] = m;
      }
    } else {
      const int q = op.a, ax = op.kind, bit = op.slot;
      const int n0 = np;
      for (int p = 0; p < n0; p++) {
        uint32_t m = meta[p];
        uint32_t x = (m >> q) & 1u;
        uint32_t z = (m >> (10 + q)) & 1u;
        uint32_t viol = (ax == 0) ? z : (ax == 1) ? (x ^ z) : x;
        if (viol) {
          uint32_t nx = 0, nz = 0, fl = 0;
          if (ax == 0)      { if (x) { nx = 0; nz = 1; fl = 1; } else { nx = 1; nz = 1; fl = 0; } }
          else if (ax == 1) { if (x) { nx = 0; nz = 1; fl = 0; } else { nx = 1; nz = 0; fl = 1; } }
          else              { if (z) { nx = 1; nz = 0; fl = 0; } else { nx = 1; nz = 1; fl = 1; } }
          if (np >= MAXP) { ovf = 1; break; }
          uint32_t m2 = m;
          m2 &= ~((1u << q) | (1u << (10 + q)));
          m2 |= (nx << q) | (nz << (10 + q));
          m2 ^= fl << 20;
          meta[np] = m2; cm[np] = cm[p]; sm[np] = sm[p] | (1u << bit);
          np++;
          cm[p] |= 1u << bit;
        }
      }
    }
  }
  if (ovf) { T.overflow = 1; return T; }
  // Y-kill compact
  int n2 = 0;
  for (int p = 0; p < np; p++) {
    uint32_t m = meta[p];
    if ((m & 1023u) & ((m >> 10) & 1023u)) continue;
    meta[n2] = m; cm[n2] = cm[p]; sm[n2] = sm[p]; n2++;
  }
  np = n2;
  // stable 2-pass radix sort of indices by 20-bit key
  int idx[MAXP] = {}; int tmp[MAXP] = {};
  for (int i = 0; i < np; i++) idx[i] = i;
  int hist[1025] = {};
  for (int i = 0; i < 1025; i++) hist[i] = 0;
  for (int i = 0; i < np; i++) hist[1 + (meta[idx[i]] & 1023u)]++;
  for (int i = 0; i < 1024; i++) hist[i + 1] += hist[i];
  for (int i = 0; i < np; i++) tmp[hist[meta[idx[i]] & 1023u]++] = idx[i];
  for (int i = 0; i < 1025; i++) hist[i] = 0;
  for (int i = 0; i < np; i++) hist[1 + ((meta[tmp[i]] >> 10) & 1023u)]++;
  for (int i = 0; i < 1024; i++) hist[i + 1] += hist[i];
  for (int i = 0; i < np; i++) idx[hist[(meta[tmp[i]] >> 10) & 1023u]++] = tmp[i];
  // group + emit (upack = ternary half-indices of the key)
  constexpr int P3[5] = {1, 3, 9, 27, 81};
  int nu = 0; uint32_t prev = 0xFFFFFFFFu;
  for (int i = 0; i < np; i++) {
    int p = idx[i];
    uint32_t key = meta[p] & 0xFFFFFu;
    if (key != prev) {
      if (nu >= MAXU) { T.overflow = 2; return T; }
      uint32_t tlo = 0, thi = 0;
      for (int w = 0; w < 5; w++) {
        uint32_t d = ((key >> w) & 1u) ? 1u : (((key >> (10 + w)) & 1u) ? 2u : 0u);
        tlo += d * (uint32_t)P3[w];
      }
      for (int w = 5; w < 10; w++) {
        uint32_t d = ((key >> w) & 1u) ? 1u : (((key >> (10 + w)) & 1u) ? 2u : 0u);
        thi += d * (uint32_t)P3[w - 5];
      }
      T.upack[nu] = tlo | (thi << 8);
      T.ustart[nu] = i; prev = key; nu++;
    }
    T.pmeta[i] = meta[p]; T.pcm[i] = cm[p]; T.psm[i] = sm[p];
  }
  T.ustart[nu] = np;
  T.np = np; T.nu = nu; T.overflow = 0;
  return T;
}

constexpr Tables TT = build_tables();
static_assert(TT.overflow == 0, "PAULI_PATH_OVERFLOW");
static_assert(TT.nu >= 1 && TT.nu <= MAXU, "PAULI_UNIQUE_COUNT_OUT_OF_RANGE");
constexpr int NU = TT.nu;
constexpr int NUPAD = ((NU + 63) / 64) * 64;   // compile-time loop bound

// ws layout (floats): pairs (C, upack) float2 at PAIRS_OFF (NUPAD entries,
// zero-padded); W_eff at WOFF; const at WOFF+10.
constexpr int PAIRS_OFF = 16;
constexpr int WOFF = PAIRS_OFF + 2 * NUPAD;

} // namespace

__device__ const Tables dTT = TT;

// ---------------------------------------------------------------------------
// Prep kernel (1 block x 256): trig + tail-fold Pauli coeffs -> (C_u, upack_u)
// pairs (zero-padded to NUPAD); MLP collapse.
// ---------------------------------------------------------------------------
__global__ __launch_bounds__(256) void prep_kernel(
    const float* __restrict__ rand_params,
    const float* __restrict__ rx_theta, const float* __restrict__ ry_theta,
    const float* __restrict__ head_w, const float* __restrict__ head_b,
    const float* __restrict__ w0, const float* __restrict__ b0,
    const float* __restrict__ w1, const float* __restrict__ b1,
    const float* __restrict__ w2, const float* __restrict__ b2,
    const float* __restrict__ w3, const float* __restrict__ b3,
    float* __restrict__ ws)
{
  const int tid = threadIdx.x;
  __shared__ float ct[32], st[32], abr[3], hwsh[10];
  __shared__ float r2[32], r1[64];

  if (tid < NOPS) {
    float t = rand_params[tid];       // FULL angle for Heisenberg conjugation
    ct[tid] = cosf(t);
    st[tid] = sinf(t);
  }
  if (tid == 30) {
    // O = M^dag Z M, Pauli coeffs (HW-verified R10):
    float tx = rx_theta[0], ty = ry_theta[0];
    abr[0] = cosf(tx) * cosf(ty);     // cZ
    abr[1] = -sinf(ty);               // cX
    abr[2] = sinf(tx) * cosf(ty);     // cY
  }
  if (tid < NW) hwsh[tid] = head_w[tid];
  __syncthreads();

  v2fp* pairs = (v2fp*)(ws + PAIRS_OFF);
  for (int u = tid; u < NUPAD; u += 256) {
    if (u < NU) {
      float acc = 0.f;
      const int i0 = dTT.ustart[u], i1 = dTT.ustart[u + 1];
      for (int i = i0; i < i1; i++) {
        uint32_t m = dTT.pmeta[i];
        float v = hwsh[(m >> 21) & 15u] * abr[(m >> 25) & 3u];
        if (m & (1u << 20)) v = -v;
        uint32_t c = dTT.pcm[i];
        while (c) { int b = __builtin_ctz(c); v *= ct[b]; c &= c - 1u; }
        uint32_t s = dTT.psm[i];
        while (s) { int b = __builtin_ctz(s); v *= st[b]; s &= s - 1u; }
        acc += v;
      }
      v2fp p; p.x = acc; p.y = __uint_as_float(dTT.upack[u]);
      pairs[u] = p;
    } else {
      v2fp p; p.x = 0.f; p.y = __uint_as_float(0u);  // C=0, idx (0,0) -> 1*1
      pairs[u] = p;
    }
  }

  // ---- MLP collapse (fully linear) ----
  if (tid < 32) {
    float acc = 0.f;
    for (int k = 0; k < 16; k++) acc += w3[k] * w2[k*32 + tid];
    r2[tid] = acc;
  }
  __syncthreads();
  if (tid < 64) {
    float acc = 0.f;
    for (int k = 0; k < 32; k++) acc += r2[k] * w1[k*64 + tid];
    r1[tid] = acc;
  }
  __syncthreads();
  if (tid < NW) {
    float acc = 0.f;
    for (int k = 0; k < 64; k++) acc += r1[k] * w0[k*NW + tid];
    ws[WOFF + tid] = acc;
  }
  if (tid == NW) {
    float acc = b3[0] + head_b[0];
    for (int k = 0; k < 16; k++) acc += w3[k] * b2[k];
    for (int k = 0; k < 32; k++) acc += r2[k] * b1[k];
    for (int k = 0; k < 64; k++) acc += r1[k] * b0[k];
    ws[WOFF + NW] = acc;
  }
}

// ---------------------------------------------------------------------------
// Eval kernel: one 64-lane wave per element. Per-wave private 2x243 LDS
// half-product tables (ternary digit: 0->1, 1->sin x_w, 2->cos x_w), built
// wave-synchronously (no barrier anywhere). String loop has a COMPILE-TIME
// trip count (NUPAD/64) -> fully unrolled, independent iterations, latency
// pipelined (the R11 regression was the runtime loop bound).
// ---------------------------------------------------------------------------
__global__ __launch_bounds__(256) void qsim_kernel(
    const float* __restrict__ x,
    const float* __restrict__ ws,
    float* __restrict__ out,
    int bsz)
{
  __shared__ float Tlo[4][256];
  __shared__ float Thi[4][256];

  const int tid = threadIdx.x;
  const int wv = (int)((blockIdx.x * blockDim.x + tid) >> 6);
  const int lane = tid & 63;
  const int e = tid >> 6;
  if (wv >= bsz) return;
  const float* xe = x + wv * NW;

  float cz[NW], sx[NW];
#pragma unroll
  for (int w = 0; w < NW; w++) {
    float xv = xe[w];
    cz[w] = __cosf(xv);
    sx[w] = __sinf(xv);
  }

  // Build the two 243-entry half-product tables (wave-private rows; the
  // wave's own in-order LDS ops make write->read safe without a barrier).
#pragma unroll
  for (int t0 = 0; t0 < 256; t0 += 64) {
    const int t = t0 + lane;
    if (t < 243) {
      float vlo = 1.f, vhi = 1.f;
      int q = t;
#pragma unroll
      for (int w = 0; w < 5; w++) {
        int d = q % 3; q /= 3;
        vlo *= (d == 1) ? sx[w]     : ((d == 2) ? cz[w]     : 1.0f);
        vhi *= (d == 1) ? sx[w + 5] : ((d == 2) ? cz[w + 5] : 1.0f);
      }
      Tlo[e][t] = vlo;
      Thi[e][t] = vhi;
    }
  }

  const v2fp* __restrict__ pairs = (const v2fp*)(ws + PAIRS_OFF);
  float acc = 0.f;
#pragma unroll
  for (int k = 0; k < NUPAD / 64; k++) {
    v2fp pr = pairs[lane + 64 * k];         // coalesced, L2-broadcast
    uint32_t pk = __float_as_uint(pr.y);
    acc = fmaf(pr.x * Tlo[e][pk & 255u], Thi[e][pk >> 8], acc);
  }

#pragma unroll
  for (int m = 1; m < 64; m <<= 1) acc += __shfl_xor(acc, m);

  if (lane == 0) {
    float cc = ws[WOFF + NW];
#pragma unroll
    for (int w = 0; w < NW; w++) cc += xe[w] * ws[WOFF + w];
    out[wv] = acc + cc;
  }
}

extern "C" void kernel_launch(void* const* d_in, const int* in_sizes, int n_in,
                              void* d_out, int out_size, void* d_ws, size_t ws_size,
                              hipStream_t stream) {
  const float* x   = (const float*)d_in[0];
  const float* rp  = (const float*)d_in[1];
  const float* rxT = (const float*)d_in[2];
  const float* ryT = (const float*)d_in[3];
  const float* hw  = (const float*)d_in[4];
  const float* hb  = (const float*)d_in[5];
  const float* w0  = (const float*)d_in[6];
  const float* b0  = (const float*)d_in[7];
  const float* w1  = (const float*)d_in[8];
  const float* b1  = (const float*)d_in[9];
  const float* w2  = (const float*)d_in[10];
  const float* b2  = (const float*)d_in[11];
  const float* w3  = (const float*)d_in[12];
  const float* b3  = (const float*)d_in[13];
  const int bsz = in_sizes[0] / NW;

  float* ws = (float*)d_ws;

  hipLaunchKernelGGL(prep_kernel, dim3(1), dim3(256), 0, stream,
                     rp, rxT, ryT, hw, hb, w0, b0, w1, b1, w2, b2, w3, b3, ws);

  const int blocks = (bsz + 3) / 4; // 4 elements (waves) per 256-thread block
  hipLaunchKernelGGL(qsim_kernel, dim3(blocks), dim3(256), 0, stream,
                     x, ws, (float*)d_out, bsz);
}